// Round 1
// baseline (11.303 us; speedup 1.0000x reference)
//
#include <hip/hip_runtime.h>

// AssociativeEmbeddingLoss on MI355X.
// pred:   (64, 1, 512, 512) f32
// target: (64, 1, 512, 512) f32
// match:  (64, 128, 2, 2)   int (harness converts int64 -> int32)
// out:    2 floats: (pull_all, push_all)
//
// pull_b = sum_i (tl_i - me_i)^2 + (br_i - me_i)^2, me = (tl+br)/2
// push_b = sum_{i != j} max(0, 1 - |me_i - me_j|)
// out0 = 0.25 * sum_b pull_b / 128
// out1 = 0.25 * sum_b push_b / (128*127)

#define AE_B      64
#define AE_NGT    128
#define AE_H      512
#define AE_W      512
#define AE_HW     (AE_H * AE_W)

__global__ __launch_bounds__(AE_NGT) void ae_loss_per_image(
    const float* __restrict__ pred,
    const float* __restrict__ target,
    const int*   __restrict__ match,
    float*       __restrict__ partials)   // [B][2]
{
    const int b = blockIdx.x;   // image
    const int t = threadIdx.x;  // 0..127 = gt index

    __shared__ float s_me[AE_NGT];
    __shared__ float s_red[4];  // {pull_w0, push_w0, pull_w1, push_w1}

    // match[b][t] = {ty, tx, by, bx} — one int4 per thread, coalesced.
    const int4 m = reinterpret_cast<const int4*>(match)[b * AE_NGT + t];
    const float tl = pred  [b * AE_HW + m.x * AE_W + m.y];
    const float br = target[b * AE_HW + m.z * AE_W + m.w];
    const float me = 0.5f * (tl + br);

    const float dtl = tl - me;
    const float dbr = br - me;
    float pull = dtl * dtl + dbr * dbr;

    s_me[t] = me;
    __syncthreads();

    float push = 0.0f;
#pragma unroll
    for (int j = 0; j < AE_NGT; ++j) {
        // LDS broadcast read (all lanes read same address) — conflict-free.
        const float v = 1.0f - fabsf(me - s_me[j]);
        if (j != t) push += fmaxf(v, 0.0f);
    }

    // Wave-64 butterfly-free down-reduce.
#pragma unroll
    for (int off = 32; off > 0; off >>= 1) {
        pull += __shfl_down(pull, off, 64);
        push += __shfl_down(push, off, 64);
    }
    const int wave = t >> 6;        // 0 or 1
    if ((t & 63) == 0) {
        s_red[wave * 2 + 0] = pull;
        s_red[wave * 2 + 1] = push;
    }
    __syncthreads();
    if (t == 0) {
        const float psum = s_red[0] + s_red[2];
        const float qsum = s_red[1] + s_red[3];
        partials[b * 2 + 0] = 0.25f * psum * (1.0f / 128.0f);
        partials[b * 2 + 1] = 0.25f * qsum * (1.0f / (128.0f * 127.0f));
    }
}

__global__ __launch_bounds__(64) void ae_loss_final(
    const float* __restrict__ partials,  // [B][2]
    float*       __restrict__ out)       // [2]
{
    const int t = threadIdx.x;  // 0..63, one per image
    const float2 pq = reinterpret_cast<const float2*>(partials)[t];
    float p = pq.x, q = pq.y;
#pragma unroll
    for (int off = 32; off > 0; off >>= 1) {
        p += __shfl_down(p, off, 64);
        q += __shfl_down(q, off, 64);
    }
    if (t == 0) {
        out[0] = p;
        out[1] = q;
    }
}

extern "C" void kernel_launch(void* const* d_in, const int* in_sizes, int n_in,
                              void* d_out, int out_size, void* d_ws, size_t ws_size,
                              hipStream_t stream) {
    const float* pred   = (const float*)d_in[0];
    const float* target = (const float*)d_in[1];
    const int*   match  = (const int*)d_in[2];
    float* out = (float*)d_out;
    float* partials = (float*)d_ws;  // needs 64*2*4 = 512 bytes

    ae_loss_per_image<<<AE_B, AE_NGT, 0, stream>>>(pred, target, match, partials);
    ae_loss_final<<<1, 64, 0, stream>>>(partials, out);
}

// Round 2
// 10.856 us; speedup vs baseline: 1.0411x; 1.0411x over previous
//
#include <hip/hip_runtime.h>

// AssociativeEmbeddingLoss on MI355X — single-dispatch fused version.
// pred:   (64, 1, 512, 512) f32
// target: (64, 1, 512, 512) f32
// match:  (64, 128, 2, 2)   int32
// out:    2 floats: (pull_all, push_all)
//
// pull_b = sum_i (tl_i - me_i)^2 + (br_i - me_i)^2, me = (tl+br)/2
// push_b = sum_{i != j} max(0, 1 - |me_i - me_j|)
// out0 = 0.25 * sum_b pull_b / 128
// out1 = 0.25 * sum_b push_b / (128*127)
//
// Cross-block reduction fused via flag+spin (block 0 = finisher):
//  - producer: plain stores of partials, __threadfence(), release-agent
//    store of 64-bit MAGIC flag (emits L2 writeback on gfx950).
//  - consumer: acquire-agent flag loads (emits buffer_inv — handles
//    non-coherent per-XCD L2s), fixed-order sum => deterministic.
//  - consumer resets flags to 0 => every replay starts from a clean state.
//    Harness poison 0xAA..AA != MAGIC, so the spin behaves correctly on the
//    first timed call too.

#define AE_B      64
#define AE_NGT    128
#define AE_W      512
#define AE_HW     (512 * 512)
#define AE_MAGIC  0x5EEDF00DCAFEBABEull

__global__ __launch_bounds__(AE_NGT) void ae_loss_fused(
    const float* __restrict__ pred,
    const float* __restrict__ target,
    const int*   __restrict__ match,
    float*       __restrict__ out,       // [2]
    float*       __restrict__ partials,  // [B] float2
    unsigned long long* __restrict__ flags)  // [B]
{
    const int b = blockIdx.x;   // image
    const int t = threadIdx.x;  // 0..127 = gt index

    __shared__ float s_me[AE_NGT];
    __shared__ float s_red[4];  // {pull_w0, push_w0, pull_w1, push_w1}

    // match[b][t] = {ty, tx, by, bx} — one int4 per thread, coalesced.
    const int4 m = reinterpret_cast<const int4*>(match)[b * AE_NGT + t];
    const float tl = pred  [b * AE_HW + m.x * AE_W + m.y];
    const float br = target[b * AE_HW + m.z * AE_W + m.w];
    const float me = 0.5f * (tl + br);

    const float dtl = tl - me;
    const float dbr = br - me;
    float pull = dtl * dtl + dbr * dbr;

    s_me[t] = me;
    __syncthreads();

    float push = 0.0f;
#pragma unroll
    for (int j = 0; j < AE_NGT; ++j) {
        // LDS broadcast read (all lanes same address) — conflict-free.
        const float v = 1.0f - fabsf(me - s_me[j]);
        if (j != t) push += fmaxf(v, 0.0f);
    }

    // Wave-64 down-reduce, then combine the block's two waves via LDS.
#pragma unroll
    for (int off = 32; off > 0; off >>= 1) {
        pull += __shfl_down(pull, off, 64);
        push += __shfl_down(push, off, 64);
    }
    if ((t & 63) == 0) {
        s_red[(t >> 6) * 2 + 0] = pull;
        s_red[(t >> 6) * 2 + 1] = push;
    }
    __syncthreads();

    if (b != 0) {
        if (t == 0) {
            const float2 pq = make_float2(s_red[0] + s_red[2],
                                          s_red[1] + s_red[3]);
            reinterpret_cast<float2*>(partials)[b] = pq;
            __threadfence();  // order partials before flag
            __hip_atomic_store(&flags[b], AE_MAGIC,
                               __ATOMIC_RELEASE, __HIP_MEMORY_SCOPE_AGENT);
        }
        return;
    }

    // ---- block 0 finisher: wave 0 only (no __syncthreads below!) ----
    if (t >= 64) return;

    float p, q;
    if (t == 0) {
        p = s_red[0] + s_red[2];
        q = s_red[1] + s_red[3];
    } else {
        // lane t waits for image t's partial (t = 1..63)
        while (__hip_atomic_load(&flags[t], __ATOMIC_ACQUIRE,
                                 __HIP_MEMORY_SCOPE_AGENT) != AE_MAGIC) {
            __builtin_amdgcn_s_sleep(1);
        }
        const float2 pq = reinterpret_cast<const float2*>(partials)[t];
        p = pq.x;
        q = pq.y;
        // reset for the next replay (value already in registers)
        __hip_atomic_store(&flags[t], 0ull,
                           __ATOMIC_RELAXED, __HIP_MEMORY_SCOPE_AGENT);
    }

#pragma unroll
    for (int off = 32; off > 0; off >>= 1) {
        p += __shfl_down(p, off, 64);
        q += __shfl_down(q, off, 64);
    }
    if (t == 0) {
        out[0] = p * (0.25f / 128.0f);
        out[1] = q * (0.25f / (128.0f * 127.0f));
    }
}

extern "C" void kernel_launch(void* const* d_in, const int* in_sizes, int n_in,
                              void* d_out, int out_size, void* d_ws, size_t ws_size,
                              hipStream_t stream) {
    const float* pred   = (const float*)d_in[0];
    const float* target = (const float*)d_in[1];
    const int*   match  = (const int*)d_in[2];
    float* out = (float*)d_out;

    // d_ws layout: [0,512)   float2 partials[64]
    //              [512,1024) u64   flags[64]
    float* partials = (float*)d_ws;
    unsigned long long* flags =
        (unsigned long long*)((char*)d_ws + 512);

    ae_loss_fused<<<AE_B, AE_NGT, 0, stream>>>(pred, target, match,
                                               out, partials, flags);
}